// Round 4
// baseline (379.329 us; speedup 1.0000x reference)
//
#include <hip/hip_runtime.h>
#include <hip/hip_bf16.h>

#define NB 32
#define SS 1024
#define DD 768

typedef __attribute__((ext_vector_type(8))) short bf16x8;
typedef __attribute__((ext_vector_type(4))) float f32x4;

__device__ inline ushort f2bf(float f) {
    union { float f; unsigned u; } x;
    x.f = f;
    unsigned r = (x.u + 0x7fffu + ((x.u >> 16) & 1u)) >> 16;
    return (ushort)r;
}

#define GLOBAL_PTR(x) ((const __attribute__((address_space(1))) void*)(x))
#define LDS_PTR(x)    ((__attribute__((address_space(3))) void*)(x))

// ---------------------------------------------------------------- K0: f32 -> bf16 flat convert of wq and wk (natural layout)
__global__ void k_cvt(const float* __restrict__ wq, const float* __restrict__ wk,
                      ushort* __restrict__ wqb, ushort* __restrict__ wkb) {
    const int i = (blockIdx.x * 256 + threadIdx.x) * 4;
    const float* src = blockIdx.y ? wk : wq;
    ushort* dst = blockIdx.y ? wkb : wqb;
    const float4 v = *(const float4*)(src + i);
    ushort4 o;
    o.x = f2bf(v.x); o.y = f2bf(v.y); o.z = f2bf(v.z); o.w = f2bf(v.w);
    *(ushort4*)(dst + i) = o;
}

// ---------------------------------------------------------------- K0b: x = bf16(emb[tokens])  (32768 x 768)
__global__ void k_gather(const int* __restrict__ tokens, const float* __restrict__ emb,
                         ushort* __restrict__ xb) {
    int i = (blockIdx.x * 256 + threadIdx.x) * 4;   // 4 f32 per thread, never crosses row
    int row = i / DD;
    int col = i - row * DD;
    int tok = tokens[row];
    const float4 v = *(const float4*)(emb + (size_t)tok * DD + col);
    ushort4 o;
    o.x = f2bf(v.x); o.y = f2bf(v.y); o.z = f2bf(v.z); o.w = f2bf(v.w);
    *(ushort4*)(xb + (size_t)row * DD + col) = o;
}

// ---------------------------------------------------------------- GEMM, T3-min pipelined (double-buffered LDS, 1 barrier/K-step)
// C = A(MxK) @ Bt(NxK)^T, bf16 in, K=768.
// MODE 0: bf16 out to Cb (ldc=DD). grids (Mtiles, Ntiles).
// MODE 1: batched f32 out to Cs (ldc=SS). 1-D grid 2048, XCD-clustered decode:
//         epochs of 512 wgs; batch = epoch*8 + wgid%8 -> all 64 tiles of a batch
//         land on one XCD (L2-resident 3MB panel pair).
template <int MODE>
__global__ __launch_bounds__(256, 2) void k_gemm(const ushort* __restrict__ A,
                                                 const ushort* __restrict__ Bt,
                                                 ushort* __restrict__ Cb,
                                                 float* __restrict__ Cs) {
    constexpr int BK = 64;
    __shared__ ushort As[2][128 * BK];
    __shared__ ushort Bs[2][128 * BK];
    const int tid = threadIdx.x;
    const int wave = tid >> 6, lane = tid & 63;

    int bx, by;
    size_t abase, bbase;
    if (MODE == 1) {
        const int wgid = blockIdx.x;
        const int g = wgid >> 9, w = wgid & 511;
        const int b = g * 8 + (w & 7);
        const int tile = w >> 3;
        bx = tile & 7; by = tile >> 3;
        abase = (size_t)b * SS * DD + (size_t)bx * 128 * DD;
        bbase = (size_t)b * SS * DD + (size_t)by * 128 * DD;
        Cs += (size_t)b * SS * SS;
    } else {
        bx = blockIdx.x; by = blockIdx.y;
        abase = (size_t)bx * 128 * DD;
        bbase = (size_t)by * 128 * DD;
    }

    const int r = tid >> 3;            // staging row 0..31
    const int cc = (tid & 7) * 8;      // staging col (bf16 units)

    auto stage = [&](int buf, int k0) {
#pragma unroll
        for (int i = 0; i < 4; i++) {
            __builtin_amdgcn_global_load_lds(GLOBAL_PTR(A + abase + (size_t)(r + i * 32) * DD + k0 + cc),
                                             LDS_PTR(&As[buf][(r + i * 32) * BK + cc]), 16, 0, 0);
            __builtin_amdgcn_global_load_lds(GLOBAL_PTR(Bt + bbase + (size_t)(r + i * 32) * DD + k0 + cc),
                                             LDS_PTR(&Bs[buf][(r + i * 32) * BK + cc]), 16, 0, 0);
        }
    };

    f32x4 acc[4][4] = {};
    const int wm = (wave >> 1) * 64, wn = (wave & 1) * 64;
    const int lr = lane & 15, lc = (lane >> 4) * 8;

    stage(0, 0);
    __syncthreads();                    // vmcnt(0): buf0 ready
    int cur = 0;
#pragma unroll 1
    for (int k0 = 0; k0 < DD; k0 += BK) {
        if (k0 + BK < DD) stage(cur ^ 1, k0 + BK);   // prefetch next tile (overlaps MFMA below)
        const ushort* as = As[cur];
        const ushort* bs = Bs[cur];
#pragma unroll
        for (int kk = 0; kk < 2; kk++) {
            bf16x8 af[4], bfv[4];
#pragma unroll
            for (int m = 0; m < 4; m++)
                af[m] = *(const bf16x8*)(as + (wm + m * 16 + lr) * BK + kk * 32 + lc);
#pragma unroll
            for (int n = 0; n < 4; n++)
                bfv[n] = *(const bf16x8*)(bs + (wn + n * 16 + lr) * BK + kk * 32 + lc);
#pragma unroll
            for (int m = 0; m < 4; m++)
#pragma unroll
                for (int n = 0; n < 4; n++)
                    acc[m][n] = __builtin_amdgcn_mfma_f32_16x16x32_bf16(af[m], bfv[n], acc[m][n], 0, 0, 0);
        }
        __syncthreads();                // drains prefetch (vmcnt 0) + protects buffer swap
        cur ^= 1;
    }

    const int rowbase = bx * 128 + wm + (lane >> 4) * 4;
    const int colbase = by * 128 + wn + (lane & 15);
    if (MODE == 0) {
#pragma unroll
        for (int m = 0; m < 4; m++)
#pragma unroll
            for (int n = 0; n < 4; n++)
#pragma unroll
                for (int j = 0; j < 4; j++)
                    Cb[(size_t)(rowbase + m * 16 + j) * DD + colbase + n * 16] = f2bf(acc[m][n][j]);
    } else {
#pragma unroll
        for (int m = 0; m < 4; m++)
#pragma unroll
            for (int n = 0; n < 4; n++)
#pragma unroll
                for (int j = 0; j < 4; j++)
                    Cs[(size_t)(rowbase + m * 16 + j) * SS + colbase + n * 16] = acc[m][n][j];
    }
}

// ---------------------------------------------------------------- K3: in-place masked softmax per row of a
__global__ __launch_bounds__(256) void k_softmax(float* __restrict__ a, const int* __restrict__ mask) {
    const int rid = blockIdx.x;
    const int b = rid >> 10, rr = rid & 1023;
    float* row = a + (size_t)b * SS * SS + (size_t)rr * SS;
    const int* mrow = mask + b * SS;
    const int t = threadIdx.x * 4;
    float4 v = *(float4*)(row + t);
    const int4 mk = *(const int4*)(mrow + t);
    float x0 = v.x + (mk.x ? -1e9f : 0.0f);
    float x1 = v.y + (mk.y ? -1e9f : 0.0f);
    float x2 = v.z + (mk.z ? -1e9f : 0.0f);
    float x3 = v.w + (mk.w ? -1e9f : 0.0f);
    float mx = fmaxf(fmaxf(x0, x1), fmaxf(x2, x3));
#pragma unroll
    for (int off = 32; off; off >>= 1) mx = fmaxf(mx, __shfl_xor(mx, off));
    __shared__ float redm[4], reds[4];
    if ((threadIdx.x & 63) == 0) redm[threadIdx.x >> 6] = mx;
    __syncthreads();
    mx = fmaxf(fmaxf(redm[0], redm[1]), fmaxf(redm[2], redm[3]));
    float e0 = expf(x0 - mx), e1 = expf(x1 - mx), e2 = expf(x2 - mx), e3 = expf(x3 - mx);
    float sm = e0 + e1 + e2 + e3;
#pragma unroll
    for (int off = 32; off; off >>= 1) sm += __shfl_xor(sm, off);
    if ((threadIdx.x & 63) == 0) reds[threadIdx.x >> 6] = sm;
    __syncthreads();
    sm = reds[0] + reds[1] + reds[2] + reds[3];
    const float inv = 1.0f / sm;
    v.x = e0 * inv; v.y = e1 * inv; v.z = e2 * inv; v.w = e3 * inv;
    *(float4*)(row + t) = v;
}

// ---------------------------------------------------------------- K4a: partial xbar[b][k] = sum_t a[b,0,t]*emb[tok[b,t]][k]
__global__ __launch_bounds__(256) void k_xbar(const float* __restrict__ a, const int* __restrict__ tokens,
                                              const float* __restrict__ emb, float* __restrict__ part) {
    const int b = blockIdx.x >> 3, c = blockIdx.x & 7;
    __shared__ float a0s[128];
    __shared__ int toks[128];
    const int tid = threadIdx.x;
    if (tid < 128) {
        a0s[tid] = a[(size_t)b * SS * SS + c * 128 + tid];
        toks[tid] = tokens[b * SS + c * 128 + tid];
    }
    __syncthreads();
    float acc0 = 0.f, acc1 = 0.f, acc2 = 0.f;
#pragma unroll 4
    for (int t = 0; t < 128; t++) {
        const float at = a0s[t];
        const float* er = emb + (size_t)toks[t] * DD;
        acc0 = fmaf(at, er[tid], acc0);
        acc1 = fmaf(at, er[tid + 256], acc1);
        acc2 = fmaf(at, er[tid + 512], acc2);
    }
    float* p = part + ((size_t)c * NB + b) * DD;
    p[tid] = acc0; p[tid + 256] = acc1; p[tid + 512] = acc2;
}

// ---------------------------------------------------------------- K5: cls[b][c] = sum_k xbar[b][k] * wv[k][c]
__global__ __launch_bounds__(128) void k_cls(const float* __restrict__ part, const float* __restrict__ wv,
                                             float* __restrict__ cls) {
    const int b = blockIdx.y, tid = threadIdx.x;
    const int c = blockIdx.x * 128 + tid;
    __shared__ float xb[DD];
#pragma unroll
    for (int j = 0; j < 6; j++) {
        const int k = tid + j * 128;
        float s = 0.f;
#pragma unroll
        for (int p = 0; p < 8; p++) s += part[((size_t)p * NB + b) * DD + k];
        xb[k] = s;
    }
    __syncthreads();
    float acc = 0.f;
#pragma unroll 8
    for (int k = 0; k < DD; k++) acc = fmaf(xb[k], wv[(size_t)k * DD + c], acc);
    cls[(size_t)b * DD + c] = acc;
}

__device__ inline float block_sum256(float v, float* red, int tid) {
#pragma unroll
    for (int off = 32; off; off >>= 1) v += __shfl_xor(v, off);
    __syncthreads();
    if ((tid & 63) == 0) red[tid >> 6] = v;
    __syncthreads();
    return red[0] + red[1] + red[2] + red[3];
}

// ---------------------------------------------------------------- K6: LayerNorm per batch
__global__ __launch_bounds__(256) void k_ln(const float* __restrict__ cls, const float* __restrict__ ln_g,
                                            const float* __restrict__ ln_b, float* __restrict__ hs) {
    const int b = blockIdx.x, tid = threadIdx.x;
    __shared__ float red[4];
    float v[3];
#pragma unroll
    for (int j = 0; j < 3; j++) v[j] = cls[(size_t)b * DD + tid + j * 256];
    const float mu = block_sum256(v[0] + v[1] + v[2], red, tid) * (1.0f / DD);
    float dv = 0.f;
#pragma unroll
    for (int j = 0; j < 3; j++) { const float d = v[j] - mu; dv += d * d; }
    __syncthreads();
    const float var = block_sum256(dv, red, tid) * (1.0f / DD);
    const float sc = 1.0f / sqrtf(var + 1e-5f);
#pragma unroll
    for (int j = 0; j < 3; j++) {
        const int d = tid + j * 256;
        hs[(size_t)b * DD + d] = (v[j] - mu) * sc * ln_g[d] + ln_b[d];
    }
}

// ---------------------------------------------------------------- K7: g = gelu(hs@w1+b1); partial logits per 128-col chunk
__global__ __launch_bounds__(128) void k_mlp(const float* __restrict__ hs, const float* __restrict__ w1,
                                             const float* __restrict__ b1, const float* __restrict__ wh,
                                             float* __restrict__ part_l) {
    const int b = blockIdx.y, tid = threadIdx.x;
    const int j = blockIdx.x * 128 + tid;
    __shared__ float h[DD];
#pragma unroll
    for (int q = 0; q < 6; q++) h[tid + q * 128] = hs[(size_t)b * DD + tid + q * 128];
    __syncthreads();
    float p = b1[j];
#pragma unroll 8
    for (int d = 0; d < DD; d++) p = fmaf(h[d], w1[(size_t)d * DD + j], p);
    const float g = 0.5f * p * (1.0f + erff(p * 0.70710678118654752f));
    float l0 = g * wh[j * 2 + 0];
    float l1 = g * wh[j * 2 + 1];
#pragma unroll
    for (int off = 32; off; off >>= 1) { l0 += __shfl_xor(l0, off); l1 += __shfl_xor(l1, off); }
    __shared__ float r0[2], r1[2];
    if ((tid & 63) == 0) { r0[tid >> 6] = l0; r1[tid >> 6] = l1; }
    __syncthreads();
    if (tid == 0) {
        part_l[((size_t)b * 6 + blockIdx.x) * 2 + 0] = r0[0] + r0[1];
        part_l[((size_t)b * 6 + blockIdx.x) * 2 + 1] = r1[0] + r1[1];
    }
}

// ---------------------------------------------------------------- K8: final logits reduce
__global__ __launch_bounds__(64) void k_final(const float* __restrict__ part_l, const float* __restrict__ bh,
                                              float* __restrict__ out) {
    const int b = threadIdx.x;
    if (b < NB) {
        float l0 = bh[0], l1 = bh[1];
#pragma unroll
        for (int c = 0; c < 6; c++) {
            l0 += part_l[((size_t)b * 6 + c) * 2 + 0];
            l1 += part_l[((size_t)b * 6 + c) * 2 + 1];
        }
        out[b * 2 + 0] = l0;
        out[b * 2 + 1] = l1;
    }
}

// ----------------------------------------------------------------
extern "C" void kernel_launch(void* const* d_in, const int* in_sizes, int n_in,
                              void* d_out, int out_size, void* d_ws, size_t ws_size,
                              hipStream_t stream) {
    const int*   tokens = (const int*)d_in[0];
    const int*   mask   = (const int*)d_in[1];
    const float* emb    = (const float*)d_in[2];
    const float* wq     = (const float*)d_in[3];
    const float* wk     = (const float*)d_in[4];
    const float* wv     = (const float*)d_in[5];
    const float* ln_g   = (const float*)d_in[6];
    const float* ln_b   = (const float*)d_in[7];
    const float* w1     = (const float*)d_in[8];
    const float* b1     = (const float*)d_in[9];
    const float* wh     = (const float*)d_in[10];
    const float* bh     = (const float*)d_in[11];
    float* out = (float*)d_out;

    char* ws = (char*)d_ws;
    const size_t XB = (size_t)NB * SS * DD * 2;   // 50,331,648 B
    const size_t WB = (size_t)DD * DD * 2;        // 1,179,648 B
    ushort* xb  = (ushort*)ws;                    // x bf16
    ushort* yb  = (ushort*)(ws + XB);             // y = x @ W bf16
    ushort* wqb = (ushort*)(ws + 2 * XB);         // wq bf16
    ushort* wkb = (ushort*)(ws + 2 * XB + WB);    // wk bf16
    ushort* Wt  = (ushort*)(ws + 2 * XB + 2 * WB);// Wt[e][d] = (wq wk^T)[d][e] bf16
    char*   p4  = ws + 2 * XB + 3 * WB;
    float*  part   = (float*)p4;                          // 8*32*768*4 = 786,432 B
    float*  cls    = (float*)(p4 + 786432);               // 32*768*4
    float*  hsb    = (float*)(p4 + 786432 + 98304);       // 32*768*4
    float*  part_l = (float*)(p4 + 786432 + 2 * 98304);   // 32*6*2*4

    float* s_region = out + 64;  // a region: B*S*S floats

    k_cvt<<<dim3(576, 2), 256, 0, stream>>>(wq, wk, wqb, wkb);
    k_gather<<<24576, 256, 0, stream>>>(tokens, emb, xb);
    // Wt = wk @ wq^T  (Wt[e][d] = sum_j wk[e,j] wq[d,j] = W[d,e])
    k_gemm<0><<<dim3(6, 6), 256, 0, stream>>>(wkb, wqb, Wt, nullptr);
    // y = x @ W  (y[s,e] = sum_d x[s,d] Wt[e,d])
    k_gemm<0><<<dim3(256, 6), 256, 0, stream>>>(xb, Wt, yb, nullptr);
    // s = y @ x^T (batched, XCD-clustered 1-D grid)
    k_gemm<1><<<2048, 256, 0, stream>>>(yb, xb, nullptr, s_region);
    k_softmax<<<32768, 256, 0, stream>>>(s_region, mask);
    k_xbar<<<256, 256, 0, stream>>>(s_region, tokens, emb, part);
    k_cls<<<dim3(6, NB), 128, 0, stream>>>(part, wv, cls);
    k_ln<<<NB, 256, 0, stream>>>(cls, ln_g, ln_b, hsb);
    k_mlp<<<dim3(6, NB), 128, 0, stream>>>(hsb, w1, b1, wh, part_l);
    k_final<<<1, 64, 0, stream>>>(part_l, bh, out);
}

// Round 5
// 337.532 us; speedup vs baseline: 1.1238x; 1.1238x over previous
//
#include <hip/hip_runtime.h>
#include <hip/hip_bf16.h>

#define NB 32
#define SS 1024
#define DD 768

typedef __attribute__((ext_vector_type(8))) short bf16x8;
typedef __attribute__((ext_vector_type(4))) float f32x4;

__device__ inline ushort f2bf(float f) {
    union { float f; unsigned u; } x;
    x.f = f;
    unsigned r = (x.u + 0x7fffu + ((x.u >> 16) & 1u)) >> 16;
    return (ushort)r;
}

#define GLOBAL_PTR(x) ((const __attribute__((address_space(1))) void*)(x))
#define LDS_PTR(x)    ((__attribute__((address_space(3))) void*)(x))

// ---------------------------------------------------------------- K0: f32 -> bf16 flat convert of wq and wk (natural layout)
__global__ void k_cvt(const float* __restrict__ wq, const float* __restrict__ wk,
                      ushort* __restrict__ wqb, ushort* __restrict__ wkb) {
    const int i = (blockIdx.x * 256 + threadIdx.x) * 4;
    const float* src = blockIdx.y ? wk : wq;
    ushort* dst = blockIdx.y ? wkb : wqb;
    const float4 v = *(const float4*)(src + i);
    ushort4 o;
    o.x = f2bf(v.x); o.y = f2bf(v.y); o.z = f2bf(v.z); o.w = f2bf(v.w);
    *(ushort4*)(dst + i) = o;
}

// ---------------------------------------------------------------- K0b: x = bf16(emb[tokens])  (32768 x 768)
__global__ void k_gather(const int* __restrict__ tokens, const float* __restrict__ emb,
                         ushort* __restrict__ xb) {
    int i = (blockIdx.x * 256 + threadIdx.x) * 4;
    int row = i / DD;
    int col = i - row * DD;
    int tok = tokens[row];
    const float4 v = *(const float4*)(emb + (size_t)tok * DD + col);
    ushort4 o;
    o.x = f2bf(v.x); o.y = f2bf(v.y); o.z = f2bf(v.z); o.w = f2bf(v.w);
    *(ushort4*)(xb + (size_t)row * DD + col) = o;
}

// ---------------------------------------------------------------- small GEMM (m97 structure, dbuf): kept for Wt = wk@wq^T only
__global__ __launch_bounds__(256, 2) void k_gemm_s(const ushort* __restrict__ A,
                                                   const ushort* __restrict__ Bt,
                                                   ushort* __restrict__ Cb) {
    constexpr int BK = 64;
    __shared__ ushort As[2][128 * BK];
    __shared__ ushort Bs[2][128 * BK];
    const int tid = threadIdx.x;
    const int wave = tid >> 6, lane = tid & 63;
    const int bx = blockIdx.x, by = blockIdx.y;
    const size_t abase = (size_t)bx * 128 * DD;
    const size_t bbase = (size_t)by * 128 * DD;
    const int r = tid >> 3;
    const int cc = (tid & 7) * 8;

    auto stage = [&](int buf, int k0) {
#pragma unroll
        for (int i = 0; i < 4; i++) {
            __builtin_amdgcn_global_load_lds(GLOBAL_PTR(A + abase + (size_t)(r + i * 32) * DD + k0 + cc),
                                             LDS_PTR(&As[buf][(r + i * 32) * BK + cc]), 16, 0, 0);
            __builtin_amdgcn_global_load_lds(GLOBAL_PTR(Bt + bbase + (size_t)(r + i * 32) * DD + k0 + cc),
                                             LDS_PTR(&Bs[buf][(r + i * 32) * BK + cc]), 16, 0, 0);
        }
    };

    f32x4 acc[4][4] = {};
    const int wm = (wave >> 1) * 64, wn = (wave & 1) * 64;
    const int lr = lane & 15, lc = (lane >> 4) * 8;

    stage(0, 0);
    __syncthreads();
    int cur = 0;
#pragma unroll 1
    for (int k0 = 0; k0 < DD; k0 += BK) {
        if (k0 + BK < DD) stage(cur ^ 1, k0 + BK);
        const ushort* as = As[cur];
        const ushort* bs = Bs[cur];
#pragma unroll
        for (int kk = 0; kk < 2; kk++) {
            bf16x8 af[4], bfv[4];
#pragma unroll
            for (int m = 0; m < 4; m++)
                af[m] = *(const bf16x8*)(as + (wm + m * 16 + lr) * BK + kk * 32 + lc);
#pragma unroll
            for (int n = 0; n < 4; n++)
                bfv[n] = *(const bf16x8*)(bs + (wn + n * 16 + lr) * BK + kk * 32 + lc);
#pragma unroll
            for (int m = 0; m < 4; m++)
#pragma unroll
                for (int n = 0; n < 4; n++)
                    acc[m][n] = __builtin_amdgcn_mfma_f32_16x16x32_bf16(af[m], bfv[n], acc[m][n], 0, 0, 0);
        }
        __syncthreads();
        cur ^= 1;
    }
    const int rowbase = bx * 128 + wm + (lane >> 4) * 4;
    const int colbase = by * 128 + wn + (lane & 15);
#pragma unroll
    for (int m = 0; m < 4; m++)
#pragma unroll
        for (int n = 0; n < 4; n++)
#pragma unroll
            for (int j = 0; j < 4; j++)
                Cb[(size_t)(rowbase + m * 16 + j) * DD + colbase + n * 16] = f2bf(acc[m][n][j]);
}

// ---------------------------------------------------------------- 256x256 8-wave 4-phase GEMM (T2 swizzle + T3 interleave + T5)
// C = A(MxK) @ Bt(NxK)^T, bf16 in, K=768, BK=64.
// MODE 0: bf16 out (ldc=DD). grid (Mtiles, Ntiles).  y = x @ Wt^T
// MODE 1: batched f32 out (ldc=SS). 1-D grid 512, XCD-clustered:
//   epochs of 128 wgs; batch = epoch*8 + w%8, tile = (w%128)/8 -> 16 tiles/batch on one XCD.
#define HALF_USH (128 * 64)
template <int MODE>
__global__ __launch_bounds__(512, 2) void k_gemm256(const ushort* __restrict__ A,
                                                    const ushort* __restrict__ Bt,
                                                    ushort* __restrict__ Cb,
                                                    float* __restrict__ Cs) {
    __shared__ ushort As[2][2][HALF_USH];   // [buf][half][row*64+col], swizzled storage
    __shared__ ushort Bs[2][2][HALF_USH];
    const int tid = threadIdx.x;
    const int wid = tid >> 6, lane = tid & 63;
    const int wm = wid >> 2, wn = wid & 3;           // wave tile: rows wm*128, cols wn*64
    const int la = lane & 15;

    int bx, by;
    size_t abase, bbase;
    if (MODE == 1) {
        const int wgid = blockIdx.x;
        const int g = wgid >> 7, w = wgid & 127;
        const int b = g * 8 + (w & 7);
        const int tile = w >> 3;
        bx = tile & 3; by = tile >> 2;
        abase = (size_t)b * SS * DD + (size_t)bx * 256 * DD;
        bbase = (size_t)b * SS * DD + (size_t)by * 256 * DD;
        Cs += (size_t)b * SS * SS;
    } else {
        bx = blockIdx.x; by = blockIdx.y;
        abase = (size_t)bx * 256 * DD;
        bbase = (size_t)by * 256 * DD;
    }
    const ushort* Ag = A + abase;
    const ushort* Bg = Bt + bbase;

    // ---- staging: per half-tile (128x64 bf16 = 16KB) 2 loads/thread, linear LDS dest,
    //      pre-swizzled global source (rule #21): chunk at LDS (r, cb) holds global (r, cb^((r&7)<<4)).
    int s_r[2], s_c[2], s_d[2];
#pragma unroll
    for (int l = 0; l < 2; l++) {
        const int L = (l * 512 + tid) * 16;          // linear byte offset in half
        const int r = L >> 7;                         // row 0..127
        const int cb = L & 127;                       // col byte 0..127
        s_r[l] = r;
        s_c[l] = (cb ^ ((r & 7) << 4)) >> 1;          // source col in elements
        s_d[l] = L >> 1;                              // dest ushort offset (linear)
    }

    auto stage_half = [&](ushort* dst, const ushort* gsrc) {
#pragma unroll
        for (int l = 0; l < 2; l++)
            __builtin_amdgcn_global_load_lds(GLOBAL_PTR(gsrc + (size_t)s_r[l] * DD + s_c[l]),
                                             LDS_PTR(dst + s_d[l]), 16, 0, 0);
    };

    // ---- read-side swizzle: row&7 == la&7 for every fragment row (bases are mult. of 16)
    const int swz = (la & 7) << 4;
    const int off_k0 = (((lane >> 4) << 4) ^ swz) >> 1;   // kk=0 col offset (ushorts)
    const int off_k1 = ((64 | ((lane >> 4) << 4)) ^ swz) >> 1;

    f32x4 acc[8][4] = {};

    // prologue: stage K-tile 0 (4 halves) into buf 0
    stage_half(&As[0][0][0], Ag);
    stage_half(&As[0][1][0], Ag + (size_t)128 * DD);
    stage_half(&Bs[0][0][0], Bg);
    stage_half(&Bs[0][1][0], Bg + (size_t)128 * DD);
    __syncthreads();

#pragma unroll 1
    for (int t = 0; t < 12; t++) {
        const int buf = t & 1;
        const ushort* Ah = &As[buf][wm][0];
        const ushort* Bh = &Bs[buf][wn >> 1][0];
        const int brow0 = (wn & 1) * 64;
        const int kt = (t + 1) * 64;
        bf16x8 bfv[4][2];
#pragma unroll
        for (int q = 0; q < 4; q++) {
            if (q == 0) {
#pragma unroll
                for (int n = 0; n < 4; n++) {
                    const int rr = brow0 + n * 16 + la;
                    bfv[n][0] = *(const bf16x8*)(Bh + rr * 64 + off_k0);
                    bfv[n][1] = *(const bf16x8*)(Bh + rr * 64 + off_k1);
                }
            }
            bf16x8 af[2][2];
#pragma unroll
            for (int dm = 0; dm < 2; dm++) {
                const int rr = (q * 2 + dm) * 16 + la;
                af[dm][0] = *(const bf16x8*)(Ah + rr * 64 + off_k0);
                af[dm][1] = *(const bf16x8*)(Ah + rr * 64 + off_k1);
            }
            if (t < 11) {   // stage half q of K-tile t+1 into other buffer
                if (q == 0) stage_half(&As[buf ^ 1][0][0], Ag + kt);
                if (q == 1) stage_half(&As[buf ^ 1][1][0], Ag + (size_t)128 * DD + kt);
                if (q == 2) stage_half(&Bs[buf ^ 1][0][0], Bg + kt);
                if (q == 3) stage_half(&Bs[buf ^ 1][1][0], Bg + (size_t)128 * DD + kt);
            }
            __builtin_amdgcn_s_setprio(1);
#pragma unroll
            for (int dm = 0; dm < 2; dm++)
#pragma unroll
                for (int n = 0; n < 4; n++)
#pragma unroll
                    for (int kk = 0; kk < 2; kk++)
                        acc[q * 2 + dm][n] = __builtin_amdgcn_mfma_f32_16x16x32_bf16(
                            af[dm][kk], bfv[n][kk], acc[q * 2 + dm][n], 0, 0, 0);
            __builtin_amdgcn_s_setprio(0);
            if (q < 3) __builtin_amdgcn_s_barrier();
        }
        __syncthreads();   // K-tile boundary: drains vmcnt(0) -> buf^1 fully staged
    }

    const int rowbase = bx * 256 + wm * 128 + (lane >> 4) * 4;
    const int colbase = by * 256 + wn * 64 + la;
    if (MODE == 0) {
#pragma unroll
        for (int m = 0; m < 8; m++)
#pragma unroll
            for (int n = 0; n < 4; n++)
#pragma unroll
                for (int j = 0; j < 4; j++)
                    Cb[(size_t)(rowbase + m * 16 + j) * DD + colbase + n * 16] = f2bf(acc[m][n][j]);
    } else {
#pragma unroll
        for (int m = 0; m < 8; m++)
#pragma unroll
            for (int n = 0; n < 4; n++)
#pragma unroll
                for (int j = 0; j < 4; j++)
                    Cs[(size_t)(rowbase + m * 16 + j) * SS + colbase + n * 16] = acc[m][n][j];
    }
}

// ---------------------------------------------------------------- K3: in-place masked softmax per row of a
__global__ __launch_bounds__(256) void k_softmax(float* __restrict__ a, const int* __restrict__ mask) {
    const int rid = blockIdx.x;
    const int b = rid >> 10, rr = rid & 1023;
    float* row = a + (size_t)b * SS * SS + (size_t)rr * SS;
    const int* mrow = mask + b * SS;
    const int t = threadIdx.x * 4;
    float4 v = *(float4*)(row + t);
    const int4 mk = *(const int4*)(mrow + t);
    float x0 = v.x + (mk.x ? -1e9f : 0.0f);
    float x1 = v.y + (mk.y ? -1e9f : 0.0f);
    float x2 = v.z + (mk.z ? -1e9f : 0.0f);
    float x3 = v.w + (mk.w ? -1e9f : 0.0f);
    float mx = fmaxf(fmaxf(x0, x1), fmaxf(x2, x3));
#pragma unroll
    for (int off = 32; off; off >>= 1) mx = fmaxf(mx, __shfl_xor(mx, off));
    __shared__ float redm[4], reds[4];
    if ((threadIdx.x & 63) == 0) redm[threadIdx.x >> 6] = mx;
    __syncthreads();
    mx = fmaxf(fmaxf(redm[0], redm[1]), fmaxf(redm[2], redm[3]));
    float e0 = expf(x0 - mx), e1 = expf(x1 - mx), e2 = expf(x2 - mx), e3 = expf(x3 - mx);
    float sm = e0 + e1 + e2 + e3;
#pragma unroll
    for (int off = 32; off; off >>= 1) sm += __shfl_xor(sm, off);
    if ((threadIdx.x & 63) == 0) reds[threadIdx.x >> 6] = sm;
    __syncthreads();
    sm = reds[0] + reds[1] + reds[2] + reds[3];
    const float inv = 1.0f / sm;
    v.x = e0 * inv; v.y = e1 * inv; v.z = e2 * inv; v.w = e3 * inv;
    *(float4*)(row + t) = v;
}

// ---------------------------------------------------------------- K4a: partial xbar[b][k] = sum_t a[b,0,t]*emb[tok[b,t]][k]
__global__ __launch_bounds__(256) void k_xbar(const float* __restrict__ a, const int* __restrict__ tokens,
                                              const float* __restrict__ emb, float* __restrict__ part) {
    const int b = blockIdx.x >> 3, c = blockIdx.x & 7;
    __shared__ float a0s[128];
    __shared__ int toks[128];
    const int tid = threadIdx.x;
    if (tid < 128) {
        a0s[tid] = a[(size_t)b * SS * SS + c * 128 + tid];
        toks[tid] = tokens[b * SS + c * 128 + tid];
    }
    __syncthreads();
    float acc0 = 0.f, acc1 = 0.f, acc2 = 0.f;
#pragma unroll 4
    for (int t = 0; t < 128; t++) {
        const float at = a0s[t];
        const float* er = emb + (size_t)toks[t] * DD;
        acc0 = fmaf(at, er[tid], acc0);
        acc1 = fmaf(at, er[tid + 256], acc1);
        acc2 = fmaf(at, er[tid + 512], acc2);
    }
    float* p = part + ((size_t)c * NB + b) * DD;
    p[tid] = acc0; p[tid + 256] = acc1; p[tid + 512] = acc2;
}

// ---------------------------------------------------------------- K5: cls[b][c] = sum_k xbar[b][k] * wv[k][c]
__global__ __launch_bounds__(128) void k_cls(const float* __restrict__ part, const float* __restrict__ wv,
                                             float* __restrict__ cls) {
    const int b = blockIdx.y, tid = threadIdx.x;
    const int c = blockIdx.x * 128 + tid;
    __shared__ float xb[DD];
#pragma unroll
    for (int j = 0; j < 6; j++) {
        const int k = tid + j * 128;
        float s = 0.f;
#pragma unroll
        for (int p = 0; p < 8; p++) s += part[((size_t)p * NB + b) * DD + k];
        xb[k] = s;
    }
    __syncthreads();
    float acc = 0.f;
#pragma unroll 8
    for (int k = 0; k < DD; k++) acc = fmaf(xb[k], wv[(size_t)k * DD + c], acc);
    cls[(size_t)b * DD + c] = acc;
}

__device__ inline float block_sum256(float v, float* red, int tid) {
#pragma unroll
    for (int off = 32; off; off >>= 1) v += __shfl_xor(v, off);
    __syncthreads();
    if ((tid & 63) == 0) red[tid >> 6] = v;
    __syncthreads();
    return red[0] + red[1] + red[2] + red[3];
}

// ---------------------------------------------------------------- K6: LayerNorm per batch
__global__ __launch_bounds__(256) void k_ln(const float* __restrict__ cls, const float* __restrict__ ln_g,
                                            const float* __restrict__ ln_b, float* __restrict__ hs) {
    const int b = blockIdx.x, tid = threadIdx.x;
    __shared__ float red[4];
    float v[3];
#pragma unroll
    for (int j = 0; j < 3; j++) v[j] = cls[(size_t)b * DD + tid + j * 256];
    const float mu = block_sum256(v[0] + v[1] + v[2], red, tid) * (1.0f / DD);
    float dv = 0.f;
#pragma unroll
    for (int j = 0; j < 3; j++) { const float d = v[j] - mu; dv += d * d; }
    __syncthreads();
    const float var = block_sum256(dv, red, tid) * (1.0f / DD);
    const float sc = 1.0f / sqrtf(var + 1e-5f);
#pragma unroll
    for (int j = 0; j < 3; j++) {
        const int d = tid + j * 256;
        hs[(size_t)b * DD + d] = (v[j] - mu) * sc * ln_g[d] + ln_b[d];
    }
}

// ---------------------------------------------------------------- K7: g = gelu(hs@w1+b1); partial logits per 128-col chunk
__global__ __launch_bounds__(128) void k_mlp(const float* __restrict__ hs, const float* __restrict__ w1,
                                             const float* __restrict__ b1, const float* __restrict__ wh,
                                             float* __restrict__ part_l) {
    const int b = blockIdx.y, tid = threadIdx.x;
    const int j = blockIdx.x * 128 + tid;
    __shared__ float h[DD];
#pragma unroll
    for (int q = 0; q < 6; q++) h[tid + q * 128] = hs[(size_t)b * DD + tid + q * 128];
    __syncthreads();
    float p = b1[j];
#pragma unroll 8
    for (int d = 0; d < DD; d++) p = fmaf(h[d], w1[(size_t)d * DD + j], p);
    const float g = 0.5f * p * (1.0f + erff(p * 0.70710678118654752f));
    float l0 = g * wh[j * 2 + 0];
    float l1 = g * wh[j * 2 + 1];
#pragma unroll
    for (int off = 32; off; off >>= 1) { l0 += __shfl_xor(l0, off); l1 += __shfl_xor(l1, off); }
    __shared__ float r0[2], r1[2];
    if ((tid & 63) == 0) { r0[tid >> 6] = l0; r1[tid >> 6] = l1; }
    __syncthreads();
    if (tid == 0) {
        part_l[((size_t)b * 6 + blockIdx.x) * 2 + 0] = r0[0] + r0[1];
        part_l[((size_t)b * 6 + blockIdx.x) * 2 + 1] = r1[0] + r1[1];
    }
}

// ---------------------------------------------------------------- K8: final logits reduce
__global__ __launch_bounds__(64) void k_final(const float* __restrict__ part_l, const float* __restrict__ bh,
                                              float* __restrict__ out) {
    const int b = threadIdx.x;
    if (b < NB) {
        float l0 = bh[0], l1 = bh[1];
#pragma unroll
        for (int c = 0; c < 6; c++) {
            l0 += part_l[((size_t)b * 6 + c) * 2 + 0];
            l1 += part_l[((size_t)b * 6 + c) * 2 + 1];
        }
        out[b * 2 + 0] = l0;
        out[b * 2 + 1] = l1;
    }
}

// ----------------------------------------------------------------
extern "C" void kernel_launch(void* const* d_in, const int* in_sizes, int n_in,
                              void* d_out, int out_size, void* d_ws, size_t ws_size,
                              hipStream_t stream) {
    const int*   tokens = (const int*)d_in[0];
    const int*   mask   = (const int*)d_in[1];
    const float* emb    = (const float*)d_in[2];
    const float* wq     = (const float*)d_in[3];
    const float* wk     = (const float*)d_in[4];
    const float* wv     = (const float*)d_in[5];
    const float* ln_g   = (const float*)d_in[6];
    const float* ln_b   = (const float*)d_in[7];
    const float* w1     = (const float*)d_in[8];
    const float* b1     = (const float*)d_in[9];
    const float* wh     = (const float*)d_in[10];
    const float* bh     = (const float*)d_in[11];
    float* out = (float*)d_out;

    char* ws = (char*)d_ws;
    const size_t XB = (size_t)NB * SS * DD * 2;   // 50,331,648 B
    const size_t WB = (size_t)DD * DD * 2;        // 1,179,648 B
    ushort* xb  = (ushort*)ws;                    // x bf16
    ushort* yb  = (ushort*)(ws + XB);             // y = x @ W bf16
    ushort* wqb = (ushort*)(ws + 2 * XB);         // wq bf16
    ushort* wkb = (ushort*)(ws + 2 * XB + WB);    // wk bf16
    ushort* Wt  = (ushort*)(ws + 2 * XB + 2 * WB);// Wt[e][d] = (wq wk^T)[d][e] bf16
    char*   p4  = ws + 2 * XB + 3 * WB;
    float*  part   = (float*)p4;                          // 8*32*768*4
    float*  cls    = (float*)(p4 + 786432);               // 32*768*4
    float*  hsb    = (float*)(p4 + 786432 + 98304);       // 32*768*4
    float*  part_l = (float*)(p4 + 786432 + 2 * 98304);   // 32*6*2*4

    float* s_region = out + 64;  // a region: B*S*S floats

    k_cvt<<<dim3(576, 2), 256, 0, stream>>>(wq, wk, wqb, wkb);
    k_gather<<<24576, 256, 0, stream>>>(tokens, emb, xb);
    // Wt = wk @ wq^T  (Wt[e][d] = sum_j wk[e,j] wq[d,j] = W[d,e])
    k_gemm_s<<<dim3(6, 6), 256, 0, stream>>>(wkb, wqb, Wt);
    // y = x @ W  (y[s,e] = sum_d x[s,d] Wt[e,d])
    k_gemm256<0><<<dim3(128, 3), 512, 0, stream>>>(xb, Wt, yb, nullptr);
    // s = y @ x^T (batched, XCD-clustered 1-D grid)
    k_gemm256<1><<<512, 512, 0, stream>>>(yb, xb, nullptr, s_region);
    k_softmax<<<32768, 256, 0, stream>>>(s_region, mask);
    k_xbar<<<256, 256, 0, stream>>>(s_region, tokens, emb, part);
    k_cls<<<dim3(6, NB), 128, 0, stream>>>(part, wv, cls);
    k_ln<<<NB, 256, 0, stream>>>(cls, ln_g, ln_b, hsb);
    k_mlp<<<dim3(6, NB), 128, 0, stream>>>(hsb, w1, b1, wh, part_l);
    k_final<<<1, 64, 0, stream>>>(part_l, bh, out);
}

// Round 6
// 318.963 us; speedup vs baseline: 1.1893x; 1.0582x over previous
//
#include <hip/hip_runtime.h>
#include <hip/hip_bf16.h>

#define NB 32
#define SS 1024
#define DD 768

typedef __attribute__((ext_vector_type(8))) short bf16x8;
typedef __attribute__((ext_vector_type(4))) float f32x4;

__device__ inline ushort f2bf(float f) {
    union { float f; unsigned u; } x;
    x.f = f;
    unsigned r = (x.u + 0x7fffu + ((x.u >> 16) & 1u)) >> 16;
    return (ushort)r;
}

#define GLOBAL_PTR(x) ((const __attribute__((address_space(1))) void*)(x))
#define LDS_PTR(x)    ((__attribute__((address_space(3))) void*)(x))

// ---------------------------------------------------------------- K0: f32 -> bf16 flat convert of wq and wk
__global__ void k_cvt(const float* __restrict__ wq, const float* __restrict__ wk,
                      ushort* __restrict__ wqb, ushort* __restrict__ wkb) {
    const int i = (blockIdx.x * 256 + threadIdx.x) * 4;
    const float* src = blockIdx.y ? wk : wq;
    ushort* dst = blockIdx.y ? wkb : wqb;
    const float4 v = *(const float4*)(src + i);
    ushort4 o;
    o.x = f2bf(v.x); o.y = f2bf(v.y); o.z = f2bf(v.z); o.w = f2bf(v.w);
    *(ushort4*)(dst + i) = o;
}

// ---------------------------------------------------------------- K0b: x = bf16(emb[tokens])  (32768 x 768)
__global__ void k_gather(const int* __restrict__ tokens, const float* __restrict__ emb,
                         ushort* __restrict__ xb) {
    int i = (blockIdx.x * 256 + threadIdx.x) * 4;
    int row = i / DD;
    int col = i - row * DD;
    int tok = tokens[row];
    const float4 v = *(const float4*)(emb + (size_t)tok * DD + col);
    ushort4 o;
    o.x = f2bf(v.x); o.y = f2bf(v.y); o.z = f2bf(v.z); o.w = f2bf(v.w);
    *(ushort4*)(xb + (size_t)row * DD + col) = o;
}

// ---------------------------------------------------------------- small GEMM (m97 structure, dbuf): Wt = wk@wq^T only
__global__ __launch_bounds__(256, 2) void k_gemm_s(const ushort* __restrict__ A,
                                                   const ushort* __restrict__ Bt,
                                                   ushort* __restrict__ Cb) {
    constexpr int BK = 64;
    __shared__ ushort As[2][128 * BK];
    __shared__ ushort Bs[2][128 * BK];
    const int tid = threadIdx.x;
    const int wave = tid >> 6, lane = tid & 63;
    const int bx = blockIdx.x, by = blockIdx.y;
    const size_t abase = (size_t)bx * 128 * DD;
    const size_t bbase = (size_t)by * 128 * DD;
    const int r = tid >> 3;
    const int cc = (tid & 7) * 8;

    auto stage = [&](int buf, int k0) {
#pragma unroll
        for (int i = 0; i < 4; i++) {
            __builtin_amdgcn_global_load_lds(GLOBAL_PTR(A + abase + (size_t)(r + i * 32) * DD + k0 + cc),
                                             LDS_PTR(&As[buf][(r + i * 32) * BK + cc]), 16, 0, 0);
            __builtin_amdgcn_global_load_lds(GLOBAL_PTR(Bt + bbase + (size_t)(r + i * 32) * DD + k0 + cc),
                                             LDS_PTR(&Bs[buf][(r + i * 32) * BK + cc]), 16, 0, 0);
        }
    };

    f32x4 acc[4][4] = {};
    const int wm = (wave >> 1) * 64, wn = (wave & 1) * 64;
    const int lr = lane & 15, lc = (lane >> 4) * 8;

    stage(0, 0);
    __syncthreads();
    int cur = 0;
#pragma unroll 1
    for (int k0 = 0; k0 < DD; k0 += BK) {
        if (k0 + BK < DD) stage(cur ^ 1, k0 + BK);
        const ushort* as = As[cur];
        const ushort* bs = Bs[cur];
#pragma unroll
        for (int kk = 0; kk < 2; kk++) {
            bf16x8 af[4], bfv[4];
#pragma unroll
            for (int m = 0; m < 4; m++)
                af[m] = *(const bf16x8*)(as + (wm + m * 16 + lr) * BK + kk * 32 + lc);
#pragma unroll
            for (int n = 0; n < 4; n++)
                bfv[n] = *(const bf16x8*)(bs + (wn + n * 16 + lr) * BK + kk * 32 + lc);
#pragma unroll
            for (int m = 0; m < 4; m++)
#pragma unroll
                for (int n = 0; n < 4; n++)
                    acc[m][n] = __builtin_amdgcn_mfma_f32_16x16x32_bf16(af[m], bfv[n], acc[m][n], 0, 0, 0);
        }
        __syncthreads();
        cur ^= 1;
    }
    const int rowbase = bx * 128 + wm + (lane >> 4) * 4;
    const int colbase = by * 128 + wn + (lane & 15);
#pragma unroll
    for (int m = 0; m < 4; m++)
#pragma unroll
        for (int n = 0; n < 4; n++)
#pragma unroll
            for (int j = 0; j < 4; j++)
                Cb[(size_t)(rowbase + m * 16 + j) * DD + colbase + n * 16] = f2bf(acc[m][n][j]);
}

// ---------------------------------------------------------------- 256x256 8-wave 4-phase GEMM (T2 swizzle + T5): y = x@Wt^T
#define HALF_USH (128 * 64)
__global__ __launch_bounds__(512, 2) void k_gemm256(const ushort* __restrict__ A,
                                                    const ushort* __restrict__ Bt,
                                                    ushort* __restrict__ Cb) {
    __shared__ ushort As[2][2][HALF_USH];
    __shared__ ushort Bs[2][2][HALF_USH];
    const int tid = threadIdx.x;
    const int wid = tid >> 6, lane = tid & 63;
    const int wm = wid >> 2, wn = wid & 3;
    const int la = lane & 15;

    const int bx = blockIdx.x, by = blockIdx.y;
    const ushort* Ag = A + (size_t)bx * 256 * DD;
    const ushort* Bg = Bt + (size_t)by * 256 * DD;

    int s_r[2], s_c[2], s_d[2];
#pragma unroll
    for (int l = 0; l < 2; l++) {
        const int L = (l * 512 + tid) * 16;
        const int r = L >> 7;
        const int cb = L & 127;
        s_r[l] = r;
        s_c[l] = (cb ^ ((r & 7) << 4)) >> 1;
        s_d[l] = L >> 1;
    }

    auto stage_half = [&](ushort* dst, const ushort* gsrc) {
#pragma unroll
        for (int l = 0; l < 2; l++)
            __builtin_amdgcn_global_load_lds(GLOBAL_PTR(gsrc + (size_t)s_r[l] * DD + s_c[l]),
                                             LDS_PTR(dst + s_d[l]), 16, 0, 0);
    };

    const int swz = (la & 7) << 4;
    const int off_k0 = (((lane >> 4) << 4) ^ swz) >> 1;
    const int off_k1 = ((64 | ((lane >> 4) << 4)) ^ swz) >> 1;

    f32x4 acc[8][4] = {};

    stage_half(&As[0][0][0], Ag);
    stage_half(&As[0][1][0], Ag + (size_t)128 * DD);
    stage_half(&Bs[0][0][0], Bg);
    stage_half(&Bs[0][1][0], Bg + (size_t)128 * DD);
    __syncthreads();

#pragma unroll 1
    for (int t = 0; t < 12; t++) {
        const int buf = t & 1;
        const ushort* Ah = &As[buf][wm][0];
        const ushort* Bh = &Bs[buf][wn >> 1][0];
        const int brow0 = (wn & 1) * 64;
        const int kt = (t + 1) * 64;
        bf16x8 bfv[4][2];
#pragma unroll
        for (int q = 0; q < 4; q++) {
            if (q == 0) {
#pragma unroll
                for (int n = 0; n < 4; n++) {
                    const int rr = brow0 + n * 16 + la;
                    bfv[n][0] = *(const bf16x8*)(Bh + rr * 64 + off_k0);
                    bfv[n][1] = *(const bf16x8*)(Bh + rr * 64 + off_k1);
                }
            }
            bf16x8 af[2][2];
#pragma unroll
            for (int dm = 0; dm < 2; dm++) {
                const int rr = (q * 2 + dm) * 16 + la;
                af[dm][0] = *(const bf16x8*)(Ah + rr * 64 + off_k0);
                af[dm][1] = *(const bf16x8*)(Ah + rr * 64 + off_k1);
            }
            if (t < 11) {
                if (q == 0) stage_half(&As[buf ^ 1][0][0], Ag + kt);
                if (q == 1) stage_half(&As[buf ^ 1][1][0], Ag + (size_t)128 * DD + kt);
                if (q == 2) stage_half(&Bs[buf ^ 1][0][0], Bg + kt);
                if (q == 3) stage_half(&Bs[buf ^ 1][1][0], Bg + (size_t)128 * DD + kt);
            }
            __builtin_amdgcn_s_setprio(1);
#pragma unroll
            for (int dm = 0; dm < 2; dm++)
#pragma unroll
                for (int n = 0; n < 4; n++)
#pragma unroll
                    for (int kk = 0; kk < 2; kk++)
                        acc[q * 2 + dm][n] = __builtin_amdgcn_mfma_f32_16x16x32_bf16(
                            af[dm][kk], bfv[n][kk], acc[q * 2 + dm][n], 0, 0, 0);
            __builtin_amdgcn_s_setprio(0);
            if (q < 3) __builtin_amdgcn_s_barrier();
        }
        __syncthreads();
    }

    const int rowbase = bx * 256 + wm * 128 + (lane >> 4) * 4;
    const int colbase = by * 256 + wn * 64 + la;
#pragma unroll
    for (int m = 0; m < 8; m++)
#pragma unroll
        for (int n = 0; n < 4; n++)
#pragma unroll
            for (int j = 0; j < 4; j++)
                Cb[(size_t)(rowbase + m * 16 + j) * DD + colbase + n * 16] = f2bf(acc[m][n][j]);
}

// ---------------------------------------------------------------- fused QK^T + masked softmax: a[b, bx*64..+64, :] final
// s = y @ x^T per batch; block = 64 rows x full 1024 cols; softmax in-block.
// grid 512 (XCD-clustered: epochs of 128; batch = g*8 + w%8, rowblock = w/8), 512 thr.
__global__ __launch_bounds__(512, 2) void k_attn(const ushort* __restrict__ Y,
                                                 const ushort* __restrict__ X,
                                                 const int* __restrict__ mask,
                                                 float* __restrict__ Aout) {
    __shared__ ushort Bsh[SS * 64];     // x-panel K-slice, swizzled storage (128 KB)
    __shared__ ushort Ash[64 * 64];     // y-tile K-slice (8 KB)
    __shared__ int    Msk[SS];          // 4 KB
    __shared__ float  RedM[8][64];      // 2 KB
    __shared__ float  RedS[8][64];      // 2 KB

    const int tid = threadIdx.x;
    const int wid = tid >> 6, lane = tid & 63;
    const int la = lane & 15, lg = lane >> 4;

    const int wgid = blockIdx.x;
    const int g = wgid >> 7, w = wgid & 127;
    const int b = g * 8 + (w & 7);
    const int bx = w >> 3;                       // row-block 0..15
    const ushort* Ag = Y + (size_t)b * SS * DD + (size_t)bx * 64 * DD;
    const ushort* Bg = X + (size_t)b * SS * DD;
    float* Ao = Aout + (size_t)b * SS * SS + (size_t)bx * 64 * SS;

    Msk[tid] = mask[b * SS + tid];
    Msk[tid + 512] = mask[b * SS + tid + 512];

    // staging geometry: load l covers row l*64 + r0, col bytes cb0..cb0+15 (pre-swizzled source)
    const int r0 = tid >> 3;                     // 0..63
    const int cb0 = (tid & 7) << 4;              // byte col 0..127
    const int sc = (cb0 ^ ((r0 & 7) << 4)) >> 1; // source col (ushorts), same for all l
    const int dofs = tid * 8;                    // dest ushort offset within 64-row half

    // read-side swizzle
    const int swz = (la & 7) << 4;
    const int off_k0 = ((lg << 4) ^ swz) >> 1;
    const int off_k1 = ((64 | (lg << 4)) ^ swz) >> 1;

    f32x4 acc[4][8] = {};

#pragma unroll 1
    for (int t = 0; t < 12; t++) {
        const int k0 = t * 64;
        __syncthreads();   // previous slice reads done -> safe to overwrite
        __builtin_amdgcn_global_load_lds(GLOBAL_PTR(Ag + (size_t)r0 * DD + k0 + sc),
                                         LDS_PTR(Ash + dofs), 16, 0, 0);
#pragma unroll
        for (int l = 0; l < 16; l++)
            __builtin_amdgcn_global_load_lds(GLOBAL_PTR(Bg + (size_t)(l * 64 + r0) * DD + k0 + sc),
                                             LDS_PTR(Bsh + l * 4096 + dofs), 16, 0, 0);
        __syncthreads();   // vmcnt(0) drain: slice ready

        bf16x8 af[4][2];
#pragma unroll
        for (int m = 0; m < 4; m++) {
            const int rr = m * 16 + la;
            af[m][0] = *(const bf16x8*)(Ash + rr * 64 + off_k0);
            af[m][1] = *(const bf16x8*)(Ash + rr * 64 + off_k1);
        }
#pragma unroll
        for (int n = 0; n < 8; n++) {
            const int rr = wid * 128 + n * 16 + la;
            bf16x8 bf0 = *(const bf16x8*)(Bsh + rr * 64 + off_k0);
            bf16x8 bf1 = *(const bf16x8*)(Bsh + rr * 64 + off_k1);
            __builtin_amdgcn_s_setprio(1);
#pragma unroll
            for (int m = 0; m < 4; m++) {
                acc[m][n] = __builtin_amdgcn_mfma_f32_16x16x32_bf16(af[m][0], bf0, acc[m][n], 0, 0, 0);
                acc[m][n] = __builtin_amdgcn_mfma_f32_16x16x32_bf16(af[m][1], bf1, acc[m][n], 0, 0, 0);
            }
            __builtin_amdgcn_s_setprio(0);
        }
    }
    __syncthreads();

    // ---- in-block masked softmax over full rows ----
    float bias[8];
#pragma unroll
    for (int n = 0; n < 8; n++)
        bias[n] = Msk[wid * 128 + n * 16 + la] ? -1e9f : 0.0f;

    float mxl[4][4];
#pragma unroll
    for (int m = 0; m < 4; m++)
#pragma unroll
        for (int j = 0; j < 4; j++) {
            float v = -3.4e38f;
#pragma unroll
            for (int n = 0; n < 8; n++) v = fmaxf(v, acc[m][n][j] + bias[n]);
#pragma unroll
            for (int off = 1; off < 16; off <<= 1) v = fmaxf(v, __shfl_xor(v, off));
            mxl[m][j] = v;
        }
    if (la == 0) {
#pragma unroll
        for (int m = 0; m < 4; m++)
#pragma unroll
            for (int j = 0; j < 4; j++)
                RedM[wid][m * 16 + lg * 4 + j] = mxl[m][j];
    }
    __syncthreads();
#pragma unroll
    for (int m = 0; m < 4; m++)
#pragma unroll
        for (int j = 0; j < 4; j++) {
            const int r = m * 16 + lg * 4 + j;
            float v = RedM[0][r];
#pragma unroll
            for (int ww = 1; ww < 8; ww++) v = fmaxf(v, RedM[ww][r]);
            mxl[m][j] = v;
        }

    float sml[4][4];
#pragma unroll
    for (int m = 0; m < 4; m++)
#pragma unroll
        for (int j = 0; j < 4; j++) {
            float s = 0.f;
#pragma unroll
            for (int n = 0; n < 8; n++) {
                const float e = __expf(acc[m][n][j] + bias[n] - mxl[m][j]);
                acc[m][n][j] = e;
                s += e;
            }
#pragma unroll
            for (int off = 1; off < 16; off <<= 1) s += __shfl_xor(s, off);
            sml[m][j] = s;
        }
    if (la == 0) {
#pragma unroll
        for (int m = 0; m < 4; m++)
#pragma unroll
            for (int j = 0; j < 4; j++)
                RedS[wid][m * 16 + lg * 4 + j] = sml[m][j];
    }
    __syncthreads();
#pragma unroll
    for (int m = 0; m < 4; m++)
#pragma unroll
        for (int j = 0; j < 4; j++) {
            const int r = m * 16 + lg * 4 + j;
            float s = RedS[0][r];
#pragma unroll
            for (int ww = 1; ww < 8; ww++) s += RedS[ww][r];
            const float inv = 1.0f / s;
#pragma unroll
            for (int n = 0; n < 8; n++)
                Ao[(size_t)r * SS + wid * 128 + n * 16 + la] = acc[m][n][j] * inv;
        }
}

// ---------------------------------------------------------------- K4a: partial xbar[b][k] = sum_t a[b,0,t]*emb[tok[b,t]][k]
__global__ __launch_bounds__(256) void k_xbar(const float* __restrict__ a, const int* __restrict__ tokens,
                                              const float* __restrict__ emb, float* __restrict__ part) {
    const int b = blockIdx.x >> 3, c = blockIdx.x & 7;
    __shared__ float a0s[128];
    __shared__ int toks[128];
    const int tid = threadIdx.x;
    if (tid < 128) {
        a0s[tid] = a[(size_t)b * SS * SS + c * 128 + tid];
        toks[tid] = tokens[b * SS + c * 128 + tid];
    }
    __syncthreads();
    float acc0 = 0.f, acc1 = 0.f, acc2 = 0.f;
#pragma unroll 4
    for (int t = 0; t < 128; t++) {
        const float at = a0s[t];
        const float* er = emb + (size_t)toks[t] * DD;
        acc0 = fmaf(at, er[tid], acc0);
        acc1 = fmaf(at, er[tid + 256], acc1);
        acc2 = fmaf(at, er[tid + 512], acc2);
    }
    float* p = part + ((size_t)c * NB + b) * DD;
    p[tid] = acc0; p[tid + 256] = acc1; p[tid + 512] = acc2;
}

// ---------------------------------------------------------------- K5: cls[b][c] = sum_k xbar[b][k] * wv[k][c]
__global__ __launch_bounds__(128) void k_cls(const float* __restrict__ part, const float* __restrict__ wv,
                                             float* __restrict__ cls) {
    const int b = blockIdx.y, tid = threadIdx.x;
    const int c = blockIdx.x * 128 + tid;
    __shared__ float xb[DD];
#pragma unroll
    for (int j = 0; j < 6; j++) {
        const int k = tid + j * 128;
        float s = 0.f;
#pragma unroll
        for (int p = 0; p < 8; p++) s += part[((size_t)p * NB + b) * DD + k];
        xb[k] = s;
    }
    __syncthreads();
    float acc = 0.f;
#pragma unroll 8
    for (int k = 0; k < DD; k++) acc = fmaf(xb[k], wv[(size_t)k * DD + c], acc);
    cls[(size_t)b * DD + c] = acc;
}

__device__ inline float block_sum256(float v, float* red, int tid) {
#pragma unroll
    for (int off = 32; off; off >>= 1) v += __shfl_xor(v, off);
    __syncthreads();
    if ((tid & 63) == 0) red[tid >> 6] = v;
    __syncthreads();
    return red[0] + red[1] + red[2] + red[3];
}

// ---------------------------------------------------------------- K6: LayerNorm per batch
__global__ __launch_bounds__(256) void k_ln(const float* __restrict__ cls, const float* __restrict__ ln_g,
                                            const float* __restrict__ ln_b, float* __restrict__ hs) {
    const int b = blockIdx.x, tid = threadIdx.x;
    __shared__ float red[4];
    float v[3];
#pragma unroll
    for (int j = 0; j < 3; j++) v[j] = cls[(size_t)b * DD + tid + j * 256];
    const float mu = block_sum256(v[0] + v[1] + v[2], red, tid) * (1.0f / DD);
    float dv = 0.f;
#pragma unroll
    for (int j = 0; j < 3; j++) { const float d = v[j] - mu; dv += d * d; }
    __syncthreads();
    const float var = block_sum256(dv, red, tid) * (1.0f / DD);
    const float sc = 1.0f / sqrtf(var + 1e-5f);
#pragma unroll
    for (int j = 0; j < 3; j++) {
        const int d = tid + j * 256;
        hs[(size_t)b * DD + d] = (v[j] - mu) * sc * ln_g[d] + ln_b[d];
    }
}

// ---------------------------------------------------------------- K7: g = gelu(hs@w1+b1); partial logits per 128-col chunk
__global__ __launch_bounds__(128) void k_mlp(const float* __restrict__ hs, const float* __restrict__ w1,
                                             const float* __restrict__ b1, const float* __restrict__ wh,
                                             float* __restrict__ part_l) {
    const int b = blockIdx.y, tid = threadIdx.x;
    const int j = blockIdx.x * 128 + tid;
    __shared__ float h[DD];
#pragma unroll
    for (int q = 0; q < 6; q++) h[tid + q * 128] = hs[(size_t)b * DD + tid + q * 128];
    __syncthreads();
    float p = b1[j];
#pragma unroll 8
    for (int d = 0; d < DD; d++) p = fmaf(h[d], w1[(size_t)d * DD + j], p);
    const float g = 0.5f * p * (1.0f + erff(p * 0.70710678118654752f));
    float l0 = g * wh[j * 2 + 0];
    float l1 = g * wh[j * 2 + 1];
#pragma unroll
    for (int off = 32; off; off >>= 1) { l0 += __shfl_xor(l0, off); l1 += __shfl_xor(l1, off); }
    __shared__ float r0[2], r1[2];
    if ((tid & 63) == 0) { r0[tid >> 6] = l0; r1[tid >> 6] = l1; }
    __syncthreads();
    if (tid == 0) {
        part_l[((size_t)b * 6 + blockIdx.x) * 2 + 0] = r0[0] + r0[1];
        part_l[((size_t)b * 6 + blockIdx.x) * 2 + 1] = r1[0] + r1[1];
    }
}

// ---------------------------------------------------------------- K8: final logits reduce
__global__ __launch_bounds__(64) void k_final(const float* __restrict__ part_l, const float* __restrict__ bh,
                                              float* __restrict__ out) {
    const int b = threadIdx.x;
    if (b < NB) {
        float l0 = bh[0], l1 = bh[1];
#pragma unroll
        for (int c = 0; c < 6; c++) {
            l0 += part_l[((size_t)b * 6 + c) * 2 + 0];
            l1 += part_l[((size_t)b * 6 + c) * 2 + 1];
        }
        out[b * 2 + 0] = l0;
        out[b * 2 + 1] = l1;
    }
}

// ----------------------------------------------------------------
extern "C" void kernel_launch(void* const* d_in, const int* in_sizes, int n_in,
                              void* d_out, int out_size, void* d_ws, size_t ws_size,
                              hipStream_t stream) {
    const int*   tokens = (const int*)d_in[0];
    const int*   mask   = (const int*)d_in[1];
    const float* emb    = (const float*)d_in[2];
    const float* wq     = (const float*)d_in[3];
    const float* wk     = (const float*)d_in[4];
    const float* wv     = (const float*)d_in[5];
    const float* ln_g   = (const float*)d_in[6];
    const float* ln_b   = (const float*)d_in[7];
    const float* w1     = (const float*)d_in[8];
    const float* b1     = (const float*)d_in[9];
    const float* wh     = (const float*)d_in[10];
    const float* bh     = (const float*)d_in[11];
    float* out = (float*)d_out;

    char* ws = (char*)d_ws;
    const size_t XB = (size_t)NB * SS * DD * 2;   // 50,331,648 B
    const size_t WB = (size_t)DD * DD * 2;        // 1,179,648 B
    ushort* xb  = (ushort*)ws;                    // x bf16
    ushort* yb  = (ushort*)(ws + XB);             // y = x @ W bf16
    ushort* wqb = (ushort*)(ws + 2 * XB);         // wq bf16
    ushort* wkb = (ushort*)(ws + 2 * XB + WB);    // wk bf16
    ushort* Wt  = (ushort*)(ws + 2 * XB + 2 * WB);// Wt[e][d] = (wq wk^T)[d][e] bf16
    char*   p4  = ws + 2 * XB + 3 * WB;
    float*  part   = (float*)p4;                          // 8*32*768*4
    float*  cls    = (float*)(p4 + 786432);               // 32*768*4
    float*  hsb    = (float*)(p4 + 786432 + 98304);       // 32*768*4
    float*  part_l = (float*)(p4 + 786432 + 2 * 98304);   // 32*6*2*4

    float* a_region = out + 64;  // a: B*S*S floats

    k_cvt<<<dim3(576, 2), 256, 0, stream>>>(wq, wk, wqb, wkb);
    k_gather<<<24576, 256, 0, stream>>>(tokens, emb, xb);
    // Wt = wk @ wq^T  (Wt[e][d] = sum_j wk[e,j] wq[d,j] = W[d,e])
    k_gemm_s<<<dim3(6, 6), 256, 0, stream>>>(wkb, wqb, Wt);
    // y = x @ W  (y[s,e] = sum_d x[s,d] Wt[e,d])
    k_gemm256<<<dim3(128, 3), 512, 0, stream>>>(xb, Wt, yb);
    // a = softmax(y @ x^T + mask), fused
    k_attn<<<512, 512, 0, stream>>>(yb, xb, mask, a_region);
    k_xbar<<<256, 256, 0, stream>>>(a_region, tokens, emb, part);
    k_cls<<<dim3(6, NB), 128, 0, stream>>>(part, wv, cls);
    k_ln<<<NB, 256, 0, stream>>>(cls, ln_g, ln_b, hsb);
    k_mlp<<<dim3(6, NB), 128, 0, stream>>>(hsb, w1, b1, wh, part_l);
    k_final<<<1, 64, 0, stream>>>(part_l, bh, out);
}